// Round 1
// baseline (229.205 us; speedup 1.0000x reference)
//
#include <hip/hip_runtime.h>
#include <hip/hip_bf16.h>
#include <hip/hip_fp16.h>
#include <stdint.h>

typedef __bf16 bf16_t;
typedef bf16_t bf16x8 __attribute__((ext_vector_type(8)));
typedef bf16_t bf16x4 __attribute__((ext_vector_type(4)));
typedef float f32x4 __attribute__((ext_vector_type(4)));

#define BM 128
#define BN 128
#define BK 32

// async global->LDS, 16B per lane. LDS dst is wave-uniform base + lane*16;
// the GLOBAL source may be arbitrary per-lane (used for the bank swizzle).
__device__ __forceinline__ void gload_lds16(const void* g, void* l) {
    __builtin_amdgcn_global_load_lds(
        (const __attribute__((address_space(1))) void*)(uintptr_t)g,
        (__attribute__((address_space(3))) void*)(uintptr_t)l,
        16, 0, 0);
}

// ---------------------------------------------------------------------------
// OLD 128x128 2-phase body — still used by qk (EPI 3) and pv (EPI 2).
// ---------------------------------------------------------------------------
template <int EPI>
__device__ __forceinline__ void gemm_body(
    bf16_t* __restrict__ As, bf16_t* __restrict__ Bs,
    const bf16_t* __restrict__ A, long lda,
    const bf16_t* __restrict__ B, long ldb,
    void* __restrict__ Cv, long ldc,
    int k0beg, int k1end, float scale, int m0, int n0,
    float* __restrict__ rs)
{
    const int tid = threadIdx.x;
    const int wid = tid >> 6, lane = tid & 63;
    const int wr = wid >> 1, wc = wid & 1;
    const int hw = lane >> 4, ln = lane & 15;

    const bf16_t *srcA[2], *srcB[2];
#pragma unroll
    for (int i = 0; i < 2; i++) {
        const int c = tid + i * 256;
        const int row = c >> 2;
        const int j = ((c & 3) - (row >> 1)) & 3;
        srcA[i] = A + (size_t)(m0 + row) * lda + j * 8;
        srcB[i] = B + (size_t)(n0 + row) * ldb + j * 8;
    }

    f32x4 acc[4][4] = {};

    for (int k0 = k0beg; k0 < k1end; k0 += BK) {
        gload_lds16(srcA[0] + k0, &As[wid * 512]);
        gload_lds16(srcA[1] + k0, &As[2048 + wid * 512]);
        gload_lds16(srcB[0] + k0, &Bs[wid * 512]);
        gload_lds16(srcB[1] + k0, &Bs[2048 + wid * 512]);
        __syncthreads();

        bf16x8 af[4], bfr[4];
#pragma unroll
        for (int t = 0; t < 4; t++) {
            const int r  = wr * 64 + t * 16 + ln;
            const int rb = wc * 64 + t * 16 + ln;
            af[t]  = *(const bf16x8*)&As[r  * BK + (((hw + (r  >> 1)) & 3) * 8)];
            bfr[t] = *(const bf16x8*)&Bs[rb * BK + (((hw + (rb >> 1)) & 3) * 8)];
        }
#pragma unroll
        for (int ti = 0; ti < 4; ti++)
#pragma unroll
            for (int tj = 0; tj < 4; tj++)
                acc[ti][tj] = __builtin_amdgcn_mfma_f32_16x16x32_bf16(
                    af[ti], bfr[tj], acc[ti][tj], 0, 0, 0);
        __syncthreads();
    }

#pragma unroll
    for (int ti = 0; ti < 4; ti++) {
        const int rbase = m0 + wr * 64 + ti * 16 + hw * 4;
        f32x4 inv4;
        if (EPI == 2) {
            const float4 r4 = *(const float4*)&rs[rbase];
            inv4[0] = 1.0f / r4.x; inv4[1] = 1.0f / r4.y;
            inv4[2] = 1.0f / r4.z; inv4[3] = 1.0f / r4.w;
        }
        float part[4] = {0.f, 0.f, 0.f, 0.f};
#pragma unroll
        for (int tj = 0; tj < 4; tj++) {
            const int col = n0 + wc * 64 + tj * 16 + ln;
#pragma unroll
            for (int rg = 0; rg < 4; rg++) {
                const size_t idx = (size_t)(rbase + rg) * ldc + col;
                if (EPI == 2) {
                    ((float*)Cv)[idx] = acc[ti][tj][rg] * inv4[rg];
                } else {  // EPI 3: exp + causal mask + row-sum
                    const float e = (col <= rbase + rg)
                                  ? __expf(acc[ti][tj][rg] * scale) : 0.0f;
                    part[rg] += e;
                    ((bf16_t*)Cv)[idx] = (bf16_t)e;
                }
            }
        }
        if (EPI == 3) {
#pragma unroll
            for (int rg = 0; rg < 4; rg++) {
                float p = part[rg];
                p += __shfl_xor(p, 1, 64);
                p += __shfl_xor(p, 2, 64);
                p += __shfl_xor(p, 4, 64);
                p += __shfl_xor(p, 8, 64);
                if (ln == 0) atomicAdd(&rs[rbase + rg], p);
            }
        }
    }
}

// ---------------------------------------------------------------------------
// NEW: 256x256 8-phase body (T2 swizzle + T3/T4 counted vmcnt + T5 setprio).
// 8 waves (512 thr) as 2(M)x4(N); per-wave 128x64 out = 8x4 16x16 frags.
// K-tile = 64, double-buffered LDS 128 KiB (2 x (A 32K + B 32K)).
// Per K-tile 4 phases {Q00,Q01,Q11,Q10}: each = {ds_read subtile | stage 2
// quarter-units | barrier | lgkmcnt(0) | sched_barrier | 16 MFMA | barrier};
// single s_waitcnt vmcnt(6) per K-tile (3 half-tiles stay in flight across
// barriers — never drained to 0 in the loop).
// Stage-unit = 64 rows x 64 k = 1 gload_lds16/thread. Units are overwritten
// only after their last ds_read phase:
//   A q0,q2 (rows 0-63/128-191, last read P1)  -> staged in P2 (tile t+2)
//   B q0,q1 (cols 0-127,        last read P2)  -> staged in P3
//   A q1,q3 (rows 64-127/192-255,last read P3) -> staged in P4
//   B q2,q3 (cols 128-255)                     -> staged in next tile's P1
// LDS swizzle: 16B-chunk rotation phys=(log+row)&7 on 128B rows -> each
// ds_read_b128 spreads 8 lanes/16B-column = conflict-free; staging
// compensates via pre-swizzled per-lane GLOBAL source (LDS dest stays linear,
// as global_load_lds requires).
// ---------------------------------------------------------------------------
template <int EPI>
__device__ __forceinline__ void gemm256_body(
    bf16_t* __restrict__ lds,
    const bf16_t* __restrict__ A, long lda,
    const bf16_t* __restrict__ B, long ldb,
    void* __restrict__ Cv, long ldc,
    int nt, int m0, int n0)
{
    const int tid = threadIdx.x;
    const int wid = tid >> 6, lane = tid & 63;
    const int wr = wid >> 2, wcn = wid & 3;
    const int hw = lane >> 4, ln = lane & 15;

    // staging: per-thread slot inside a 64-row unit. row-in-unit and the
    // swizzle-compensated logical chunk are lane-constant across units.
    const int srow = (wid << 3) + (lane >> 3);          // 0..63
    const int clog = ((lane & 7) - (lane >> 3)) & 7;    // global chunk for slot
    const bf16_t* sA = A + (size_t)(m0 + srow) * lda + clog * 8;
    const bf16_t* sB = B + (size_t)(n0 + srow) * ldb + clog * 8;
    char* ldsc = (char*)lds;
    const int wb = wid << 10;                           // wave slice in a unit

#define STG_A(bf, q, kt) gload_lds16(sA + (size_t)(q) * 64 * lda + (size_t)(kt) * 64, \
                                     ldsc + (bf) * 65536 + (q) * 8192 + wb)
#define STG_B(bf, q, kt) gload_lds16(sB + (size_t)(q) * 64 * ldb + (size_t)(kt) * 64, \
                                     ldsc + (bf) * 65536 + 32768 + (q) * 8192 + wb)

    // ds_read addressing: row ≡ ln (mod 8) for every fragment, so the
    // rotated chunk offset is lane-constant per k-step.
    const int c0 = ((hw + ln) & 7) << 4;
    const int c1 = ((hw + ln + 4) & 7) << 4;
    const int aR = (wr * 128 + ln) * 128;               // byte, A row base
    const int bR = 32768 + (wcn * 64 + ln) * 128;       // byte, B row base

#define RDA(bf, fr, ks) (*(const bf16x8*)(ldsc + (bf) * 65536 + aR + (fr) * 2048 + ((ks) ? c1 : c0)))
#define RDB(bf, fc, ks) (*(const bf16x8*)(ldsc + (bf) * 65536 + bR + (fc) * 2048 + ((ks) ? c1 : c0)))

    f32x4 acc[8][4] = {};

    // prologue: tile0 complete (8 units), tile1 units 1-6. vmcnt(6) -> tile0
    // landed, tile1's first 6 units in flight.
    STG_A(0, 0, 0); STG_A(0, 2, 0); STG_B(0, 0, 0); STG_B(0, 1, 0);
    STG_A(0, 1, 0); STG_A(0, 3, 0); STG_B(0, 2, 0); STG_B(0, 3, 0);
    STG_A(1, 0, 1); STG_A(1, 2, 1); STG_B(1, 0, 1); STG_B(1, 1, 1);
    STG_A(1, 1, 1); STG_A(1, 3, 1);
    asm volatile("s_waitcnt vmcnt(6)" ::: "memory");
    __builtin_amdgcn_s_barrier();

    for (int t = 0; t < nt; ++t) {
        const int bc = t & 1, bn = bc ^ 1;
        const int kt1 = (t + 1) & (nt - 1);   // wraps harmlessly at the tail
        const int kt2 = (t + 2) & (nt - 1);
        bf16x8 af[4][2], bl[2][2], bh[2][2];

        // ---- P1: read a_lo + b_lo; stage next tile's B q2,q3; MFMA Q(0,0)
#pragma unroll
        for (int fr = 0; fr < 4; ++fr) {
            af[fr][0] = RDA(bc, fr, 0);
            af[fr][1] = RDA(bc, fr, 1);
        }
#pragma unroll
        for (int fc = 0; fc < 2; ++fc) {
            bl[fc][0] = RDB(bc, fc, 0);
            bl[fc][1] = RDB(bc, fc, 1);
        }
        STG_B(bn, 2, kt1); STG_B(bn, 3, kt1);
        __builtin_amdgcn_s_barrier();
        asm volatile("s_waitcnt lgkmcnt(0)" ::: "memory");
        __builtin_amdgcn_sched_barrier(0);
        __builtin_amdgcn_s_setprio(1);
#pragma unroll
        for (int fr = 0; fr < 4; ++fr)
#pragma unroll
            for (int fc = 0; fc < 2; ++fc)
#pragma unroll
                for (int ks = 0; ks < 2; ++ks)
                    acc[fr][fc] = __builtin_amdgcn_mfma_f32_16x16x32_bf16(
                        af[fr][ks], bl[fc][ks], acc[fr][fc], 0, 0, 0);
        __builtin_amdgcn_s_setprio(0);
        __builtin_amdgcn_s_barrier();

        // ---- P2: read b_hi; stage t+2 A q0,q2 (last read was P1); Q(0,1)
#pragma unroll
        for (int fc = 0; fc < 2; ++fc) {
            bh[fc][0] = RDB(bc, fc + 2, 0);
            bh[fc][1] = RDB(bc, fc + 2, 1);
        }
        STG_A(bc, 0, kt2); STG_A(bc, 2, kt2);
        __builtin_amdgcn_s_barrier();
        asm volatile("s_waitcnt lgkmcnt(0)" ::: "memory");
        __builtin_amdgcn_sched_barrier(0);
        __builtin_amdgcn_s_setprio(1);
#pragma unroll
        for (int fr = 0; fr < 4; ++fr)
#pragma unroll
            for (int fc = 0; fc < 2; ++fc)
#pragma unroll
                for (int ks = 0; ks < 2; ++ks)
                    acc[fr][fc + 2] = __builtin_amdgcn_mfma_f32_16x16x32_bf16(
                        af[fr][ks], bh[fc][ks], acc[fr][fc + 2], 0, 0, 0);
        __builtin_amdgcn_s_setprio(0);
        __builtin_amdgcn_s_barrier();

        // ---- P3: read a_hi; stage t+2 B q0,q1 (last read was P2); Q(1,1)
#pragma unroll
        for (int fr = 0; fr < 4; ++fr) {
            af[fr][0] = RDA(bc, fr + 4, 0);
            af[fr][1] = RDA(bc, fr + 4, 1);
        }
        STG_B(bc, 0, kt2); STG_B(bc, 1, kt2);
        __builtin_amdgcn_s_barrier();
        asm volatile("s_waitcnt lgkmcnt(0)" ::: "memory");
        __builtin_amdgcn_sched_barrier(0);
        __builtin_amdgcn_s_setprio(1);
#pragma unroll
        for (int fr = 0; fr < 4; ++fr)
#pragma unroll
            for (int fc = 0; fc < 2; ++fc)
#pragma unroll
                for (int ks = 0; ks < 2; ++ks)
                    acc[fr + 4][fc + 2] = __builtin_amdgcn_mfma_f32_16x16x32_bf16(
                        af[fr][ks], bh[fc][ks], acc[fr + 4][fc + 2], 0, 0, 0);
        __builtin_amdgcn_s_setprio(0);
        __builtin_amdgcn_s_barrier();

        // ---- P4: no reads; stage t+2 A q1,q3 (last read was P3); Q(1,0);
        //      counted vmcnt -> tile t+1 fully landed, t+2 units 1-6 in flight
        STG_A(bc, 1, kt2); STG_A(bc, 3, kt2);
        __builtin_amdgcn_s_setprio(1);
#pragma unroll
        for (int fr = 0; fr < 4; ++fr)
#pragma unroll
            for (int fc = 0; fc < 2; ++fc)
#pragma unroll
                for (int ks = 0; ks < 2; ++ks)
                    acc[fr + 4][fc] = __builtin_amdgcn_mfma_f32_16x16x32_bf16(
                        af[fr][ks], bl[fc][ks], acc[fr + 4][fc], 0, 0, 0);
        __builtin_amdgcn_s_setprio(0);
        asm volatile("s_waitcnt vmcnt(6)" ::: "memory");
        __builtin_amdgcn_s_barrier();
    }

    // drain the (harmless, wrapped) trailing prefetches before reusing nothing
    asm volatile("s_waitcnt vmcnt(0)" ::: "memory");

    // epilogue: C/D layout col=lane&15, row=(lane>>4)*4+reg
#pragma unroll
    for (int fr = 0; fr < 8; ++fr) {
        const int rbase = m0 + wr * 128 + fr * 16 + hw * 4;
#pragma unroll
        for (int fc = 0; fc < 4; ++fc) {
            const int col = n0 + wcn * 64 + fc * 16 + ln;
            if (EPI == 4) {
                // transposed bf16 into Vt[b][d][s]
                const int bb = rbase >> 11;
                const int s  = rbase & 2047;
                const int d  = col - 2048;
                bf16x4 o;
#pragma unroll
                for (int rg = 0; rg < 4; rg++) o[rg] = (bf16_t)acc[fr][fc][rg];
                *(bf16x4*)&((bf16_t*)Cv)[(size_t)bb * 2097152 + (size_t)d * 2048 + s] = o;
            } else {
#pragma unroll
                for (int rg = 0; rg < 4; rg++)
                    ((bf16_t*)Cv)[(size_t)(rbase + rg) * ldc + col] =
                        (bf16_t)acc[fr][fc][rg];
            }
        }
    }
#undef STG_A
#undef STG_B
#undef RDA
#undef RDB
}

// ---------------------------------------------------------------------------
// GEMM1: [K|Q] = x*W^T row-major into QKVb (8192x2048); V written transposed
// into Vt[b][d][s]. M=8192 (32 mblk of 256), N=3072 (12 nblk of 256).
// grid 384 x 512 thr. XCD swizzle: xcd owns mblk [4x,4x+4), nblk walks slow.
// ---------------------------------------------------------------------------
__global__ __launch_bounds__(512, 2) void gemm1_qkv(
    const bf16_t* __restrict__ xb, const bf16_t* __restrict__ Wb,
    bf16_t* __restrict__ QKVb, bf16_t* __restrict__ Vt)
{
    __shared__ __align__(16) bf16_t lds[65536];   // 128 KiB
    const int lin = blockIdx.x;                   // 0..383
    const int xcd = lin & 7;
    const int j   = lin >> 3;                     // 0..47
    const int mblk = xcd * 4 + (j & 3);           // 0..31
    const int nblk = j >> 2;                      // 0..11
    const int m0 = mblk * 256, n0 = nblk * 256;
    if (nblk < 8)
        gemm256_body<0>(lds, xb, 1024, Wb, 1024, QKVb, 2048, 16, m0, n0);
    else
        gemm256_body<4>(lds, xb, 1024, Wb, 1024, Vt, 2048, 16, m0, n0);
}

// ---------------------------------------------------------------------------
// GEMM2+exp: E = exp(scale*Q K^T) per batch, causal-masked, bf16; row sums
// accumulated into rowsum (f32, pre-zeroed). 544 blocks, heavy-first.
// ---------------------------------------------------------------------------
__global__ __launch_bounds__(256) void qk_gemm(
    const bf16_t* __restrict__ QKVb, bf16_t* __restrict__ E,
    float* __restrict__ rowsum)
{
    __shared__ __align__(16) bf16_t As[BM * BK];
    __shared__ __align__(16) bf16_t Bs[BN * BK];
    const int b = blockIdx.x & 3;
    int rem = blockIdx.x >> 2;             // 0..135
    int my = 15, nx = 0;
#pragma unroll
    for (int m = 15; m >= 0; --m) {        // heavy strips first
        if (rem < m + 1) { my = m; nx = rem; break; }
        rem -= m + 1;
    }
    const bf16_t* base = QKVb + (size_t)b * (2048L * 2048);
    gemm_body<3>(As, Bs,
                 base + 1024, 2048,        // Q
                 base, 2048,               // K
                 E + (size_t)b * (2048L * 2048), 2048,
                 0, 1024, 0.03125f, my * BM, nx * BN,
                 rowsum + b * 2048);
}

// ---------------------------------------------------------------------------
// GEMM3: out = (E * Vt^T) / rowsum per batch -> f32. tri-K (Keff=m0+128),
// grid 512, heavy strips first, batch fastest.
// ---------------------------------------------------------------------------
__global__ __launch_bounds__(256) void gemm3_pv(
    const bf16_t* __restrict__ E, const bf16_t* __restrict__ Vt,
    const float* __restrict__ rowsum, float* __restrict__ out)
{
    __shared__ __align__(16) bf16_t As[BM * BK];
    __shared__ __align__(16) bf16_t Bs[BN * BK];
    const int id = blockIdx.x;
    const int strip = 15 - (id >> 5);      // heavy first
    const int nx = (id >> 2) & 7;
    const int b = id & 3;
    const int m0 = strip * BM;
    gemm_body<2>(As, Bs,
                 E + (size_t)b * (2048L * 2048), 2048,
                 Vt + (size_t)b * (1024L * 2048), 2048,
                 out + (size_t)b * (2048L * 1024), 1024,
                 0, m0 + BM, 1.0f, m0, nx * BN,
                 (float*)rowsum + b * 2048);
}

// ---------------------------------------------------------------------------
// Merged input casts: blocks [0,8192) cast x, [8192,11264) cast W,
// [11264,11272) zero the rowsum array (4x2048 f32).
__global__ __launch_bounds__(256) void cast_all(
    const float* __restrict__ x,
    const float* __restrict__ Wk, const float* __restrict__ Wq,
    const float* __restrict__ Wv,
    bf16_t* __restrict__ xb, bf16_t* __restrict__ Wb,
    float* __restrict__ rowsum)
{
    const int blk = blockIdx.x;
    if (blk >= 11264) {
        const size_t i = ((size_t)(blk - 11264) * 256 + threadIdx.x) * 4;
        *(float4*)(rowsum + i) = make_float4(0.f, 0.f, 0.f, 0.f);
        return;
    }
    const float* src;
    bf16_t* dst;
    if (blk < 8192) {
        const size_t i = ((size_t)blk * 256 + threadIdx.x) * 4;
        src = x + i;
        dst = xb + i;
    } else {
        const size_t j = ((size_t)(blk - 8192) * 256 + threadIdx.x) * 4;
        dst = Wb + j;
        if (j < (size_t)1048576)      src = Wk + j;
        else if (j < (size_t)2097152) src = Wq + (j - 1048576);
        else                          src = Wv + (j - 2097152);
    }
    const float4 v = *(const float4*)src;
    bf16x4 o;
    o.x = (bf16_t)v.x; o.y = (bf16_t)v.y; o.z = (bf16_t)v.z; o.w = (bf16_t)v.w;
    *(bf16x4*)dst = o;
}

// ---------------------------------------------------------------------------
extern "C" void kernel_launch(void* const* d_in, const int* in_sizes, int n_in,
                              void* d_out, int out_size, void* d_ws, size_t ws_size,
                              hipStream_t stream)
{
    const float* x  = (const float*)d_in[0];
    const float* Wk = (const float*)d_in[1];
    const float* Wq = (const float*)d_in[2];
    const float* Wv = (const float*)d_in[3];
    char* ws = (char*)d_ws;

    // ws layout (81 MB used):
    //   [0,32)   QKVb bf16 8192x2048  ([K|Q] columns only; V goes to Vt)
    //   [32,48)  Vt   bf16 4 x 1024x2048 (written transposed by GEMM1)
    //   [48,64)  xb   bf16 8192x1024   (dead after GEMM1)
    //   [64,70)  Wb   bf16 3072x1024   (dead after GEMM1)
    //   [48,80)  E    bf16 4 x 2048x2048 exp-logits (aliases xb+Wb, both dead)
    //   [80,81)  rowsum f32 4x2048 (zeroed by cast_all)
    bf16_t* QKVb   = (bf16_t*)(ws);
    bf16_t* Vt     = (bf16_t*)(ws + ((size_t)32 << 20));
    bf16_t* xb     = (bf16_t*)(ws + ((size_t)48 << 20));
    bf16_t* Wb     = (bf16_t*)(ws + ((size_t)64 << 20));
    bf16_t* E      = (bf16_t*)(ws + ((size_t)48 << 20));
    float*  rowsum = (float*)(ws + ((size_t)80 << 20));
    float*  out    = (float*)d_out;

    // 1. cast inputs to bf16 + zero rowsum
    cast_all<<<11272, 256, 0, stream>>>(x, Wk, Wq, Wv, xb, Wb, rowsum);

    // 2. GEMM1: 256^2 8-phase body, 384 blocks x 512 thr
    gemm1_qkv<<<384, 512, 0, stream>>>(xb, Wb, QKVb, Vt);

    // 3. GEMM2: causal exp(QK^T) -> bf16 E + atomic row sums (no softmax kernel)
    qk_gemm<<<544, 256, 0, stream>>>(QKVb, E, rowsum);

    // 4. GEMM3: out = (E Vt^T)/rowsum, tri-K, heavy-first
    gemm3_pv<<<512, 256, 0, stream>>>(E, Vt, rowsum, out);
}

// Round 3
// 224.914 us; speedup vs baseline: 1.0191x; 1.0191x over previous
//
#include <hip/hip_runtime.h>
#include <hip/hip_bf16.h>
#include <hip/hip_fp16.h>
#include <stdint.h>

typedef __bf16 bf16_t;
typedef bf16_t bf16x8 __attribute__((ext_vector_type(8)));
typedef bf16_t bf16x4 __attribute__((ext_vector_type(4)));
typedef float f32x4 __attribute__((ext_vector_type(4)));

#define BM 128
#define BN 128
#define BK 32

// async global->LDS, 16B per lane. LDS dst is wave-uniform base + lane*16;
// the GLOBAL source may be arbitrary per-lane (used for the bank swizzle).
__device__ __forceinline__ void gload_lds16(const void* g, void* l) {
    __builtin_amdgcn_global_load_lds(
        (const __attribute__((address_space(1))) void*)(uintptr_t)g,
        (__attribute__((address_space(3))) void*)(uintptr_t)l,
        16, 0, 0);
}

// ---------------------------------------------------------------------------
// 128x128 2-phase body — used by gemm1_v (EPI 4), qk (EPI 3), pv (EPI 2).
// ---------------------------------------------------------------------------
template <int EPI>
__device__ __forceinline__ void gemm_body(
    bf16_t* __restrict__ As, bf16_t* __restrict__ Bs,
    const bf16_t* __restrict__ A, long lda,
    const bf16_t* __restrict__ B, long ldb,
    void* __restrict__ Cv, long ldc,
    int k0beg, int k1end, float scale, int m0, int n0,
    float* __restrict__ rs)
{
    const int tid = threadIdx.x;
    const int wid = tid >> 6, lane = tid & 63;
    const int wr = wid >> 1, wc = wid & 1;
    const int hw = lane >> 4, ln = lane & 15;

    const bf16_t *srcA[2], *srcB[2];
#pragma unroll
    for (int i = 0; i < 2; i++) {
        const int c = tid + i * 256;
        const int row = c >> 2;
        const int j = ((c & 3) - (row >> 1)) & 3;
        srcA[i] = A + (size_t)(m0 + row) * lda + j * 8;
        srcB[i] = B + (size_t)(n0 + row) * ldb + j * 8;
    }

    f32x4 acc[4][4] = {};

    for (int k0 = k0beg; k0 < k1end; k0 += BK) {
        gload_lds16(srcA[0] + k0, &As[wid * 512]);
        gload_lds16(srcA[1] + k0, &As[2048 + wid * 512]);
        gload_lds16(srcB[0] + k0, &Bs[wid * 512]);
        gload_lds16(srcB[1] + k0, &Bs[2048 + wid * 512]);
        __syncthreads();

        bf16x8 af[4], bfr[4];
#pragma unroll
        for (int t = 0; t < 4; t++) {
            const int r  = wr * 64 + t * 16 + ln;
            const int rb = wc * 64 + t * 16 + ln;
            af[t]  = *(const bf16x8*)&As[r  * BK + (((hw + (r  >> 1)) & 3) * 8)];
            bfr[t] = *(const bf16x8*)&Bs[rb * BK + (((hw + (rb >> 1)) & 3) * 8)];
        }
#pragma unroll
        for (int ti = 0; ti < 4; ti++)
#pragma unroll
            for (int tj = 0; tj < 4; tj++)
                acc[ti][tj] = __builtin_amdgcn_mfma_f32_16x16x32_bf16(
                    af[ti], bfr[tj], acc[ti][tj], 0, 0, 0);
        __syncthreads();
    }

#pragma unroll
    for (int ti = 0; ti < 4; ti++) {
        const int rbase = m0 + wr * 64 + ti * 16 + hw * 4;
        f32x4 inv4;
        if (EPI == 2) {
            const float4 r4 = *(const float4*)&rs[rbase];
            inv4[0] = 1.0f / r4.x; inv4[1] = 1.0f / r4.y;
            inv4[2] = 1.0f / r4.z; inv4[3] = 1.0f / r4.w;
        }
        float part[4] = {0.f, 0.f, 0.f, 0.f};
#pragma unroll
        for (int tj = 0; tj < 4; tj++) {
            const int col = n0 + wc * 64 + tj * 16 + ln;
            if (EPI == 4) {
                // transposed bf16: 4 consecutive rows -> 8B contiguous in Vt
                const int bb = rbase >> 11;
                const int s  = rbase & 2047;
                const int d  = col - 2048;
                bf16x4 o;
#pragma unroll
                for (int rg = 0; rg < 4; rg++) o[rg] = (bf16_t)acc[ti][tj][rg];
                *(bf16x4*)&((bf16_t*)Cv)[(size_t)bb * 2097152 + (size_t)d * 2048 + s] = o;
            } else {
#pragma unroll
                for (int rg = 0; rg < 4; rg++) {
                    const size_t idx = (size_t)(rbase + rg) * ldc + col;
                    if (EPI == 2) {
                        ((float*)Cv)[idx] = acc[ti][tj][rg] * inv4[rg];
                    } else {  // EPI 3: exp + causal mask + row-sum
                        const float e = (col <= rbase + rg)
                                      ? __expf(acc[ti][tj][rg] * scale) : 0.0f;
                        part[rg] += e;
                        ((bf16_t*)Cv)[idx] = (bf16_t)e;
                    }
                }
            }
        }
        if (EPI == 3) {
#pragma unroll
            for (int rg = 0; rg < 4; rg++) {
                float p = part[rg];
                p += __shfl_xor(p, 1, 64);
                p += __shfl_xor(p, 2, 64);
                p += __shfl_xor(p, 4, 64);
                p += __shfl_xor(p, 8, 64);
                if (ln == 0) atomicAdd(&rs[rbase + rg], p);
            }
        }
    }
}

// ---------------------------------------------------------------------------
// 256x256 8-phase body (T2 swizzle + T3/T4 counted vmcnt + T5 setprio).
// 8 waves (512 thr) as 2(M)x4(N); per-wave 128x64 out = 8x4 16x16 frags.
// K-tile = 64, double-buffered LDS 128 KiB. 4 phases per K-tile; single
// s_waitcnt vmcnt(6) per K-tile (prefetches stay in flight across barriers).
// Stage-unit = 64 rows x 64 k = 1 gload_lds16/thread; units overwritten only
// after their last ds_read phase. LDS swizzle: 16B-chunk rotation
// phys=(log+row)&7 on 128B rows (conflict-free ds_read_b128, verified 0).
// ---------------------------------------------------------------------------
__device__ __forceinline__ void gemm256_body(
    bf16_t* __restrict__ lds,
    const bf16_t* __restrict__ A, long lda,
    const bf16_t* __restrict__ B, long ldb,
    bf16_t* __restrict__ C, long ldc,
    int nt, int m0, int n0)
{
    const int tid = threadIdx.x;
    const int wid = tid >> 6, lane = tid & 63;
    const int wr = wid >> 2, wcn = wid & 3;
    const int hw = lane >> 4, ln = lane & 15;

    const int srow = (wid << 3) + (lane >> 3);          // 0..63
    const int clog = ((lane & 7) - (lane >> 3)) & 7;    // swizzle-compensated chunk
    const bf16_t* sA = A + (size_t)(m0 + srow) * lda + clog * 8;
    const bf16_t* sB = B + (size_t)(n0 + srow) * ldb + clog * 8;
    char* ldsc = (char*)lds;
    const int wb = wid << 10;

#define STG_A(bf, q, kt) gload_lds16(sA + (size_t)(q) * 64 * lda + (size_t)(kt) * 64, \
                                     ldsc + (bf) * 65536 + (q) * 8192 + wb)
#define STG_B(bf, q, kt) gload_lds16(sB + (size_t)(q) * 64 * ldb + (size_t)(kt) * 64, \
                                     ldsc + (bf) * 65536 + 32768 + (q) * 8192 + wb)

    const int c0 = ((hw + ln) & 7) << 4;
    const int c1 = ((hw + ln + 4) & 7) << 4;
    const int aR = (wr * 128 + ln) * 128;
    const int bR = 32768 + (wcn * 64 + ln) * 128;

#define RDA(bf, fr, ks) (*(const bf16x8*)(ldsc + (bf) * 65536 + aR + (fr) * 2048 + ((ks) ? c1 : c0)))
#define RDB(bf, fc, ks) (*(const bf16x8*)(ldsc + (bf) * 65536 + bR + (fc) * 2048 + ((ks) ? c1 : c0)))

    f32x4 acc[8][4] = {};

    // prologue: tile0 complete (8 units), tile1 units 1-6 in flight.
    STG_A(0, 0, 0); STG_A(0, 2, 0); STG_B(0, 0, 0); STG_B(0, 1, 0);
    STG_A(0, 1, 0); STG_A(0, 3, 0); STG_B(0, 2, 0); STG_B(0, 3, 0);
    STG_A(1, 0, 1); STG_A(1, 2, 1); STG_B(1, 0, 1); STG_B(1, 1, 1);
    STG_A(1, 1, 1); STG_A(1, 3, 1);
    asm volatile("s_waitcnt vmcnt(6)" ::: "memory");
    __builtin_amdgcn_s_barrier();

    for (int t = 0; t < nt; ++t) {
        const int bc = t & 1, bn = bc ^ 1;
        const int kt1 = (t + 1) & (nt - 1);
        const int kt2 = (t + 2) & (nt - 1);
        bf16x8 af[4][2], bl[2][2], bh[2][2];

        // ---- P1: read a_lo + b_lo; stage t+1's B q2,q3; MFMA Q(0,0)
#pragma unroll
        for (int fr = 0; fr < 4; ++fr) {
            af[fr][0] = RDA(bc, fr, 0);
            af[fr][1] = RDA(bc, fr, 1);
        }
#pragma unroll
        for (int fc = 0; fc < 2; ++fc) {
            bl[fc][0] = RDB(bc, fc, 0);
            bl[fc][1] = RDB(bc, fc, 1);
        }
        STG_B(bn, 2, kt1); STG_B(bn, 3, kt1);
        __builtin_amdgcn_s_barrier();
        asm volatile("s_waitcnt lgkmcnt(0)" ::: "memory");
        __builtin_amdgcn_sched_barrier(0);
        __builtin_amdgcn_s_setprio(1);
#pragma unroll
        for (int fr = 0; fr < 4; ++fr)
#pragma unroll
            for (int fc = 0; fc < 2; ++fc)
#pragma unroll
                for (int ks = 0; ks < 2; ++ks)
                    acc[fr][fc] = __builtin_amdgcn_mfma_f32_16x16x32_bf16(
                        af[fr][ks], bl[fc][ks], acc[fr][fc], 0, 0, 0);
        __builtin_amdgcn_s_setprio(0);
        __builtin_amdgcn_s_barrier();

        // ---- P2: read b_hi; stage t+2 A q0,q2; MFMA Q(0,1)
#pragma unroll
        for (int fc = 0; fc < 2; ++fc) {
            bh[fc][0] = RDB(bc, fc + 2, 0);
            bh[fc][1] = RDB(bc, fc + 2, 1);
        }
        STG_A(bc, 0, kt2); STG_A(bc, 2, kt2);
        __builtin_amdgcn_s_barrier();
        asm volatile("s_waitcnt lgkmcnt(0)" ::: "memory");
        __builtin_amdgcn_sched_barrier(0);
        __builtin_amdgcn_s_setprio(1);
#pragma unroll
        for (int fr = 0; fr < 4; ++fr)
#pragma unroll
            for (int fc = 0; fc < 2; ++fc)
#pragma unroll
                for (int ks = 0; ks < 2; ++ks)
                    acc[fr][fc + 2] = __builtin_amdgcn_mfma_f32_16x16x32_bf16(
                        af[fr][ks], bh[fc][ks], acc[fr][fc + 2], 0, 0, 0);
        __builtin_amdgcn_s_setprio(0);
        __builtin_amdgcn_s_barrier();

        // ---- P3: read a_hi; stage t+2 B q0,q1; MFMA Q(1,1)
#pragma unroll
        for (int fr = 0; fr < 4; ++fr) {
            af[fr][0] = RDA(bc, fr + 4, 0);
            af[fr][1] = RDA(bc, fr + 4, 1);
        }
        STG_B(bc, 0, kt2); STG_B(bc, 1, kt2);
        __builtin_amdgcn_s_barrier();
        asm volatile("s_waitcnt lgkmcnt(0)" ::: "memory");
        __builtin_amdgcn_sched_barrier(0);
        __builtin_amdgcn_s_setprio(1);
#pragma unroll
        for (int fr = 0; fr < 4; ++fr)
#pragma unroll
            for (int fc = 0; fc < 2; ++fc)
#pragma unroll
                for (int ks = 0; ks < 2; ++ks)
                    acc[fr + 4][fc + 2] = __builtin_amdgcn_mfma_f32_16x16x32_bf16(
                        af[fr][ks], bh[fc][ks], acc[fr + 4][fc + 2], 0, 0, 0);
        __builtin_amdgcn_s_setprio(0);
        __builtin_amdgcn_s_barrier();

        // ---- P4: stage t+2 A q1,q3; MFMA Q(1,0); counted vmcnt
        STG_A(bc, 1, kt2); STG_A(bc, 3, kt2);
        __builtin_amdgcn_s_setprio(1);
#pragma unroll
        for (int fr = 0; fr < 4; ++fr)
#pragma unroll
            for (int fc = 0; fc < 2; ++fc)
#pragma unroll
                for (int ks = 0; ks < 2; ++ks)
                    acc[fr + 4][fc] = __builtin_amdgcn_mfma_f32_16x16x32_bf16(
                        af[fr][ks], bl[fc][ks], acc[fr + 4][fc], 0, 0, 0);
        __builtin_amdgcn_s_setprio(0);
        asm volatile("s_waitcnt vmcnt(6)" ::: "memory");
        __builtin_amdgcn_s_barrier();
    }

    asm volatile("s_waitcnt vmcnt(0)" ::: "memory");

    // epilogue: C/D layout col=lane&15, row=(lane>>4)*4+reg
#pragma unroll
    for (int fr = 0; fr < 8; ++fr) {
        const int rbase = m0 + wr * 128 + fr * 16 + hw * 4;
#pragma unroll
        for (int fc = 0; fc < 4; ++fc) {
            const int col = n0 + wcn * 64 + fc * 16 + ln;
#pragma unroll
            for (int rg = 0; rg < 4; rg++)
                C[(size_t)(rbase + rg) * ldc + col] = (bf16_t)acc[fr][fc][rg];
        }
    }
#undef STG_A
#undef STG_B
#undef RDA
#undef RDB
}

// ---------------------------------------------------------------------------
// GEMM1a: [K|Q] = x*W^T row-major into QKVb (8192x2048). M=8192 (32 mblk of
// 256), N=2048 (8 nblk of 256) -> grid EXACTLY 256 = one clean round at
// 1 block/CU. XCD swizzle: xcd owns mblk [4x,4x+4).
// ---------------------------------------------------------------------------
__global__ __launch_bounds__(512, 2) void gemm1_kq(
    const bf16_t* __restrict__ xb, const bf16_t* __restrict__ Wb,
    bf16_t* __restrict__ QKVb)
{
    __shared__ __align__(16) bf16_t lds[65536];   // 128 KiB
    const int lin = blockIdx.x;                   // 0..255
    const int xcd = lin & 7;
    const int j   = lin >> 3;                     // 0..31
    const int mblk = xcd * 4 + (j & 3);           // 0..31
    const int nblk = j >> 2;                      // 0..7
    gemm256_body(lds, xb, 1024, Wb, 1024, QKVb, 2048, 16, mblk * 256, nblk * 256);
}

// ---------------------------------------------------------------------------
// GEMM1b: V = x*Wv^T written transposed into Vt[b][d][s]. Old proven 128^2
// body, EPI 4. M=8192 (64 mblk), N=1024 (8 nblk, cols 2048..3071 of Wb).
// grid 512 x 256 thr (~2 blocks/CU). XCD swizzle: xcd owns mblk [8x,8x+8).
// ---------------------------------------------------------------------------
__global__ __launch_bounds__(256) void gemm1_v(
    const bf16_t* __restrict__ xb, const bf16_t* __restrict__ Wb,
    bf16_t* __restrict__ Vt)
{
    __shared__ __align__(16) bf16_t As[BM * BK];
    __shared__ __align__(16) bf16_t Bs[BN * BK];
    const int lin = blockIdx.x;            // 0..511
    const int xcd = lin & 7;
    const int j   = lin >> 3;              // 0..63
    const int mblk = xcd * 8 + (j >> 3);   // 0..63
    const int nblk = j & 7;                // 0..7
    gemm_body<4>(As, Bs, xb, 1024, Wb, 1024, Vt, 2048,
                 0, 1024, 1.0f, mblk * BM, 2048 + nblk * BN, nullptr);
}

// ---------------------------------------------------------------------------
// GEMM2+exp: E = exp(scale*Q K^T) per batch, causal-masked, bf16; row sums
// accumulated into rowsum (f32, pre-zeroed). 544 blocks, heavy-first.
// ---------------------------------------------------------------------------
__global__ __launch_bounds__(256) void qk_gemm(
    const bf16_t* __restrict__ QKVb, bf16_t* __restrict__ E,
    float* __restrict__ rowsum)
{
    __shared__ __align__(16) bf16_t As[BM * BK];
    __shared__ __align__(16) bf16_t Bs[BN * BK];
    const int b = blockIdx.x & 3;
    int rem = blockIdx.x >> 2;             // 0..135
    int my = 15, nx = 0;
#pragma unroll
    for (int m = 15; m >= 0; --m) {        // heavy strips first
        if (rem < m + 1) { my = m; nx = rem; break; }
        rem -= m + 1;
    }
    const bf16_t* base = QKVb + (size_t)b * (2048L * 2048);
    gemm_body<3>(As, Bs,
                 base + 1024, 2048,        // Q
                 base, 2048,               // K
                 E + (size_t)b * (2048L * 2048), 2048,
                 0, 1024, 0.03125f, my * BM, nx * BN,
                 rowsum + b * 2048);
}

// ---------------------------------------------------------------------------
// GEMM3: out = (E * Vt^T) / rowsum per batch -> f32. tri-K (Keff=m0+128),
// grid 512, heavy strips first, batch fastest.
// ---------------------------------------------------------------------------
__global__ __launch_bounds__(256) void gemm3_pv(
    const bf16_t* __restrict__ E, const bf16_t* __restrict__ Vt,
    const float* __restrict__ rowsum, float* __restrict__ out)
{
    __shared__ __align__(16) bf16_t As[BM * BK];
    __shared__ __align__(16) bf16_t Bs[BN * BK];
    const int id = blockIdx.x;
    const int strip = 15 - (id >> 5);      // heavy first
    const int nx = (id >> 2) & 7;
    const int b = id & 3;
    const int m0 = strip * BM;
    gemm_body<2>(As, Bs,
                 E + (size_t)b * (2048L * 2048), 2048,
                 Vt + (size_t)b * (1024L * 2048), 2048,
                 out + (size_t)b * (2048L * 1024), 1024,
                 0, m0 + BM, 1.0f, m0, nx * BN,
                 (float*)rowsum + b * 2048);
}

// ---------------------------------------------------------------------------
// Merged input casts: blocks [0,8192) cast x, [8192,11264) cast W,
// [11264,11272) zero the rowsum array (4x2048 f32).
__global__ __launch_bounds__(256) void cast_all(
    const float* __restrict__ x,
    const float* __restrict__ Wk, const float* __restrict__ Wq,
    const float* __restrict__ Wv,
    bf16_t* __restrict__ xb, bf16_t* __restrict__ Wb,
    float* __restrict__ rowsum)
{
    const int blk = blockIdx.x;
    if (blk >= 11264) {
        const size_t i = ((size_t)(blk - 11264) * 256 + threadIdx.x) * 4;
        *(float4*)(rowsum + i) = make_float4(0.f, 0.f, 0.f, 0.f);
        return;
    }
    const float* src;
    bf16_t* dst;
    if (blk < 8192) {
        const size_t i = ((size_t)blk * 256 + threadIdx.x) * 4;
        src = x + i;
        dst = xb + i;
    } else {
        const size_t j = ((size_t)(blk - 8192) * 256 + threadIdx.x) * 4;
        dst = Wb + j;
        if (j < (size_t)1048576)      src = Wk + j;
        else if (j < (size_t)2097152) src = Wq + (j - 1048576);
        else                          src = Wv + (j - 2097152);
    }
    const float4 v = *(const float4*)src;
    bf16x4 o;
    o.x = (bf16_t)v.x; o.y = (bf16_t)v.y; o.z = (bf16_t)v.z; o.w = (bf16_t)v.w;
    *(bf16x4*)dst = o;
}

// ---------------------------------------------------------------------------
extern "C" void kernel_launch(void* const* d_in, const int* in_sizes, int n_in,
                              void* d_out, int out_size, void* d_ws, size_t ws_size,
                              hipStream_t stream)
{
    const float* x  = (const float*)d_in[0];
    const float* Wk = (const float*)d_in[1];
    const float* Wq = (const float*)d_in[2];
    const float* Wv = (const float*)d_in[3];
    char* ws = (char*)d_ws;

    // ws layout (81 MB used):
    //   [0,32)   QKVb bf16 8192x2048  ([K|Q] columns only; V goes to Vt)
    //   [32,48)  Vt   bf16 4 x 1024x2048 (written transposed by GEMM1b)
    //   [48,64)  xb   bf16 8192x1024   (dead after GEMM1)
    //   [64,70)  Wb   bf16 3072x1024   (dead after GEMM1)
    //   [48,80)  E    bf16 4 x 2048x2048 exp-logits (aliases xb+Wb, both dead)
    //   [80,81)  rowsum f32 4x2048 (zeroed by cast_all)
    bf16_t* QKVb   = (bf16_t*)(ws);
    bf16_t* Vt     = (bf16_t*)(ws + ((size_t)32 << 20));
    bf16_t* xb     = (bf16_t*)(ws + ((size_t)48 << 20));
    bf16_t* Wb     = (bf16_t*)(ws + ((size_t)64 << 20));
    bf16_t* E      = (bf16_t*)(ws + ((size_t)48 << 20));
    float*  rowsum = (float*)(ws + ((size_t)80 << 20));
    float*  out    = (float*)d_out;

    // 1. cast inputs to bf16 + zero rowsum
    cast_all<<<11272, 256, 0, stream>>>(x, Wk, Wq, Wv, xb, Wb, rowsum);

    // 2a. GEMM1 K|Q: 256^2 8-phase body, exactly 256 blocks (no tail)
    gemm1_kq<<<256, 512, 0, stream>>>(xb, Wb, QKVb);

    // 2b. GEMM1 V: old 128^2 body, transposed store into Vt
    gemm1_v<<<512, 256, 0, stream>>>(xb, Wb, Vt);

    // 3. GEMM2: causal exp(QK^T) -> bf16 E + atomic row sums (no softmax kernel)
    qk_gemm<<<544, 256, 0, stream>>>(QKVb, E, rowsum);

    // 4. GEMM3: out = (E Vt^T)/rowsum, tri-K, heavy-first
    gemm3_pv<<<512, 256, 0, stream>>>(E, Vt, rowsum, out);
}

// Round 4
// 224.752 us; speedup vs baseline: 1.0198x; 1.0007x over previous
//
#include <hip/hip_runtime.h>
#include <hip/hip_bf16.h>
#include <hip/hip_fp16.h>
#include <stdint.h>

typedef __bf16 bf16_t;
typedef bf16_t bf16x8 __attribute__((ext_vector_type(8)));
typedef bf16_t bf16x4 __attribute__((ext_vector_type(4)));
typedef float f32x4 __attribute__((ext_vector_type(4)));

#define BM 128
#define BN 128
#define BK 64

// async global->LDS, 16B per lane. LDS dst is wave-uniform base + lane*16;
// the GLOBAL source may be arbitrary per-lane (used for the bank swizzle).
__device__ __forceinline__ void gload_lds16(const void* g, void* l) {
    __builtin_amdgcn_global_load_lds(
        (const __attribute__((address_space(1))) void*)(uintptr_t)g,
        (__attribute__((address_space(3))) void*)(uintptr_t)l,
        16, 0, 0);
}

// ---------------------------------------------------------------------------
// 128x128 body, BK=64 (r4: was 32 — one barrier-pair + one vmcnt drain per
// 64 K instead of two; LDS 32 KiB/block keeps >=5 blocks/CU by LDS).
// Staging: per matrix 128 rows x 8 chunks(16B) = 1024 chunks, 4/thread
// (i=0..3), row = tid>>3 + 32i, slot = tid&7. Swizzle: slot s of row holds
// global chunk ((s - (row>>1)) & 7); j is i-invariant since 32i>>1 ≡ 0 mod 8.
// Read: logical chunk l = h*4+hw at phys ((l + (r>>1)) & 7) — row-pair
// rotation spreads 16 rows over all 32 banks (2 lanes/bank = free, m136).
// EPI: 2 = f32 store / rs[row]  (gemm3)
//      3 = exp+causal bf16 store + atomic row-sum into rs  (qk)
//      4 = bf16 transposed into Vt[b][d][s]  (gemm1 V)
// ---------------------------------------------------------------------------
template <int EPI>
__device__ __forceinline__ void gemm_body(
    bf16_t* __restrict__ As, bf16_t* __restrict__ Bs,
    const bf16_t* __restrict__ A, long lda,
    const bf16_t* __restrict__ B, long ldb,
    void* __restrict__ Cv, long ldc,
    int k0beg, int k1end, float scale, int m0, int n0,
    float* __restrict__ rs)
{
    const int tid = threadIdx.x;
    const int wid = tid >> 6, lane = tid & 63;
    const int wr = wid >> 1, wc = wid & 1;
    const int hw = lane >> 4, ln = lane & 15;

    const int row0 = tid >> 3;                       // 0..31
    const int jj = ((tid & 7) - (row0 >> 1)) & 7;    // swizzle-compensated chunk
    const bf16_t* srcA0 = A + (size_t)(m0 + row0) * lda + jj * 8;
    const bf16_t* srcB0 = B + (size_t)(n0 + row0) * ldb + jj * 8;

    f32x4 acc[4][4] = {};

    for (int k0 = k0beg; k0 < k1end; k0 += BK) {
#pragma unroll
        for (int i = 0; i < 4; i++) {
            gload_lds16(srcA0 + (size_t)(32 * i) * lda + k0, &As[tid * 8 + i * 2048]);
            gload_lds16(srcB0 + (size_t)(32 * i) * ldb + k0, &Bs[tid * 8 + i * 2048]);
        }
        __syncthreads();

#pragma unroll
        for (int h = 0; h < 2; h++) {
            bf16x8 af[4], bfr[4];
#pragma unroll
            for (int t = 0; t < 4; t++) {
                const int r  = wr * 64 + t * 16 + ln;
                const int rb = wc * 64 + t * 16 + ln;
                af[t]  = *(const bf16x8*)&As[r  * BK + ((((h << 2) + hw) + (r  >> 1)) & 7) * 8];
                bfr[t] = *(const bf16x8*)&Bs[rb * BK + ((((h << 2) + hw) + (rb >> 1)) & 7) * 8];
            }
#pragma unroll
            for (int ti = 0; ti < 4; ti++)
#pragma unroll
                for (int tj = 0; tj < 4; tj++)
                    acc[ti][tj] = __builtin_amdgcn_mfma_f32_16x16x32_bf16(
                        af[ti], bfr[tj], acc[ti][tj], 0, 0, 0);
        }
        __syncthreads();
    }

    // epilogue: C/D layout col=lane&15, row=(lane>>4)*4+reg (m89-verified)
#pragma unroll
    for (int ti = 0; ti < 4; ti++) {
        const int rbase = m0 + wr * 64 + ti * 16 + hw * 4;
        f32x4 inv4;
        if (EPI == 2) {
            const float4 r4 = *(const float4*)&rs[rbase];
            inv4[0] = 1.0f / r4.x; inv4[1] = 1.0f / r4.y;
            inv4[2] = 1.0f / r4.z; inv4[3] = 1.0f / r4.w;
        }
        float part[4] = {0.f, 0.f, 0.f, 0.f};
#pragma unroll
        for (int tj = 0; tj < 4; tj++) {
            const int col = n0 + wc * 64 + tj * 16 + ln;
            if (EPI == 4) {
                // transposed bf16: 4 consecutive rows -> 8B contiguous in Vt
                const int bb = rbase >> 11;
                const int s  = rbase & 2047;
                const int d  = col - 2048;
                bf16x4 o;
#pragma unroll
                for (int rg = 0; rg < 4; rg++) o[rg] = (bf16_t)acc[ti][tj][rg];
                *(bf16x4*)&((bf16_t*)Cv)[(size_t)bb * 2097152 + (size_t)d * 2048 + s] = o;
            } else {
#pragma unroll
                for (int rg = 0; rg < 4; rg++) {
                    const size_t idx = (size_t)(rbase + rg) * ldc + col;
                    if (EPI == 2) {
                        ((float*)Cv)[idx] = acc[ti][tj][rg] * inv4[rg];
                    } else {  // EPI 3: exp + causal mask + row-sum
                        const float e = (col <= rbase + rg)
                                      ? __expf(acc[ti][tj][rg] * scale) : 0.0f;
                        part[rg] += e;
                        ((bf16_t*)Cv)[idx] = (bf16_t)e;
                    }
                }
            }
        }
        if (EPI == 3) {
#pragma unroll
            for (int rg = 0; rg < 4; rg++) {
                float p = part[rg];
                p += __shfl_xor(p, 1, 64);
                p += __shfl_xor(p, 2, 64);
                p += __shfl_xor(p, 4, 64);
                p += __shfl_xor(p, 8, 64);
                if (ln == 0) atomicAdd(&rs[rbase + rg], p);
            }
        }
    }
}

// ---------------------------------------------------------------------------
// 256x256 8-phase body for gemm1 K|Q (r3: ~parity with old body at K=1024;
// kept — not a regression, and a future schedule fix slots in here).
// ---------------------------------------------------------------------------
__device__ __forceinline__ void gemm256_body(
    bf16_t* __restrict__ lds,
    const bf16_t* __restrict__ A, long lda,
    const bf16_t* __restrict__ B, long ldb,
    bf16_t* __restrict__ C, long ldc,
    int nt, int m0, int n0)
{
    const int tid = threadIdx.x;
    const int wid = tid >> 6, lane = tid & 63;
    const int wr = wid >> 2, wcn = wid & 3;
    const int hw = lane >> 4, ln = lane & 15;

    const int srow = (wid << 3) + (lane >> 3);          // 0..63
    const int clog = ((lane & 7) - (lane >> 3)) & 7;    // swizzle-compensated chunk
    const bf16_t* sA = A + (size_t)(m0 + srow) * lda + clog * 8;
    const bf16_t* sB = B + (size_t)(n0 + srow) * ldb + clog * 8;
    char* ldsc = (char*)lds;
    const int wb = wid << 10;

#define STG_A(bf, q, kt) gload_lds16(sA + (size_t)(q) * 64 * lda + (size_t)(kt) * 64, \
                                     ldsc + (bf) * 65536 + (q) * 8192 + wb)
#define STG_B(bf, q, kt) gload_lds16(sB + (size_t)(q) * 64 * ldb + (size_t)(kt) * 64, \
                                     ldsc + (bf) * 65536 + 32768 + (q) * 8192 + wb)

    const int c0 = ((hw + ln) & 7) << 4;
    const int c1 = ((hw + ln + 4) & 7) << 4;
    const int aR = (wr * 128 + ln) * 128;
    const int bR = 32768 + (wcn * 64 + ln) * 128;

#define RDA(bf, fr, ks) (*(const bf16x8*)(ldsc + (bf) * 65536 + aR + (fr) * 2048 + ((ks) ? c1 : c0)))
#define RDB(bf, fc, ks) (*(const bf16x8*)(ldsc + (bf) * 65536 + bR + (fc) * 2048 + ((ks) ? c1 : c0)))

    f32x4 acc[8][4] = {};

    STG_A(0, 0, 0); STG_A(0, 2, 0); STG_B(0, 0, 0); STG_B(0, 1, 0);
    STG_A(0, 1, 0); STG_A(0, 3, 0); STG_B(0, 2, 0); STG_B(0, 3, 0);
    STG_A(1, 0, 1); STG_A(1, 2, 1); STG_B(1, 0, 1); STG_B(1, 1, 1);
    STG_A(1, 1, 1); STG_A(1, 3, 1);
    asm volatile("s_waitcnt vmcnt(6)" ::: "memory");
    __builtin_amdgcn_s_barrier();

    for (int t = 0; t < nt; ++t) {
        const int bc = t & 1, bn = bc ^ 1;
        const int kt1 = (t + 1) & (nt - 1);
        const int kt2 = (t + 2) & (nt - 1);
        bf16x8 af[4][2], bl[2][2], bh[2][2];

        // ---- P1: read a_lo + b_lo; stage t+1's B q2,q3; MFMA Q(0,0)
#pragma unroll
        for (int fr = 0; fr < 4; ++fr) {
            af[fr][0] = RDA(bc, fr, 0);
            af[fr][1] = RDA(bc, fr, 1);
        }
#pragma unroll
        for (int fc = 0; fc < 2; ++fc) {
            bl[fc][0] = RDB(bc, fc, 0);
            bl[fc][1] = RDB(bc, fc, 1);
        }
        STG_B(bn, 2, kt1); STG_B(bn, 3, kt1);
        __builtin_amdgcn_s_barrier();
        asm volatile("s_waitcnt lgkmcnt(0)" ::: "memory");
        __builtin_amdgcn_sched_barrier(0);
        __builtin_amdgcn_s_setprio(1);
#pragma unroll
        for (int fr = 0; fr < 4; ++fr)
#pragma unroll
            for (int fc = 0; fc < 2; ++fc)
#pragma unroll
                for (int ks = 0; ks < 2; ++ks)
                    acc[fr][fc] = __builtin_amdgcn_mfma_f32_16x16x32_bf16(
                        af[fr][ks], bl[fc][ks], acc[fr][fc], 0, 0, 0);
        __builtin_amdgcn_s_setprio(0);
        __builtin_amdgcn_s_barrier();

        // ---- P2: read b_hi; stage t+2 A q0,q2; MFMA Q(0,1)
#pragma unroll
        for (int fc = 0; fc < 2; ++fc) {
            bh[fc][0] = RDB(bc, fc + 2, 0);
            bh[fc][1] = RDB(bc, fc + 2, 1);
        }
        STG_A(bc, 0, kt2); STG_A(bc, 2, kt2);
        __builtin_amdgcn_s_barrier();
        asm volatile("s_waitcnt lgkmcnt(0)" ::: "memory");
        __builtin_amdgcn_sched_barrier(0);
        __builtin_amdgcn_s_setprio(1);
#pragma unroll
        for (int fr = 0; fr < 4; ++fr)
#pragma unroll
            for (int fc = 0; fc < 2; ++fc)
#pragma unroll
                for (int ks = 0; ks < 2; ++ks)
                    acc[fr][fc + 2] = __builtin_amdgcn_mfma_f32_16x16x32_bf16(
                        af[fr][ks], bh[fc][ks], acc[fr][fc + 2], 0, 0, 0);
        __builtin_amdgcn_s_setprio(0);
        __builtin_amdgcn_s_barrier();

        // ---- P3: read a_hi; stage t+2 B q0,q1; MFMA Q(1,1)
#pragma unroll
        for (int fr = 0; fr < 4; ++fr) {
            af[fr][0] = RDA(bc, fr + 4, 0);
            af[fr][1] = RDA(bc, fr + 4, 1);
        }
        STG_B(bc, 0, kt2); STG_B(bc, 1, kt2);
        __builtin_amdgcn_s_barrier();
        asm volatile("s_waitcnt lgkmcnt(0)" ::: "memory");
        __builtin_amdgcn_sched_barrier(0);
        __builtin_amdgcn_s_setprio(1);
#pragma unroll
        for (int fr = 0; fr < 4; ++fr)
#pragma unroll
            for (int fc = 0; fc < 2; ++fc)
#pragma unroll
                for (int ks = 0; ks < 2; ++ks)
                    acc[fr + 4][fc + 2] = __builtin_amdgcn_mfma_f32_16x16x32_bf16(
                        af[fr][ks], bh[fc][ks], acc[fr + 4][fc + 2], 0, 0, 0);
        __builtin_amdgcn_s_setprio(0);
        __builtin_amdgcn_s_barrier();

        // ---- P4: stage t+2 A q1,q3; MFMA Q(1,0); counted vmcnt
        STG_A(bc, 1, kt2); STG_A(bc, 3, kt2);
        __builtin_amdgcn_s_setprio(1);
#pragma unroll
        for (int fr = 0; fr < 4; ++fr)
#pragma unroll
            for (int fc = 0; fc < 2; ++fc)
#pragma unroll
                for (int ks = 0; ks < 2; ++ks)
                    acc[fr + 4][fc] = __builtin_amdgcn_mfma_f32_16x16x32_bf16(
                        af[fr][ks], bl[fc][ks], acc[fr + 4][fc], 0, 0, 0);
        __builtin_amdgcn_s_setprio(0);
        asm volatile("s_waitcnt vmcnt(6)" ::: "memory");
        __builtin_amdgcn_s_barrier();
    }

    asm volatile("s_waitcnt vmcnt(0)" ::: "memory");

#pragma unroll
    for (int fr = 0; fr < 8; ++fr) {
        const int rbase = m0 + wr * 128 + fr * 16 + hw * 4;
#pragma unroll
        for (int fc = 0; fc < 4; ++fc) {
            const int col = n0 + wcn * 64 + fc * 16 + ln;
#pragma unroll
            for (int rg = 0; rg < 4; rg++)
                C[(size_t)(rbase + rg) * ldc + col] = (bf16_t)acc[fr][fc][rg];
        }
    }
#undef STG_A
#undef STG_B
#undef RDA
#undef RDB
}

// ---------------------------------------------------------------------------
// GEMM1a: [K|Q] = x*W^T row-major into QKVb (8192x2048). grid exactly 256.
// ---------------------------------------------------------------------------
__global__ __launch_bounds__(512, 2) void gemm1_kq(
    const bf16_t* __restrict__ xb, const bf16_t* __restrict__ Wb,
    bf16_t* __restrict__ QKVb)
{
    __shared__ __align__(16) bf16_t lds[65536];   // 128 KiB
    const int lin = blockIdx.x;                   // 0..255
    const int xcd = lin & 7;
    const int j   = lin >> 3;                     // 0..31
    const int mblk = xcd * 4 + (j & 3);           // 0..31
    const int nblk = j >> 2;                      // 0..7
    gemm256_body(lds, xb, 1024, Wb, 1024, QKVb, 2048, 16, mblk * 256, nblk * 256);
}

// ---------------------------------------------------------------------------
// FUSED V-projection + QK-exp (r4): independent once kq is done, so one
// dispatch co-schedules them (~4 blocks/CU vs 2 serial dispatches at <=2/CU).
// Requires non-aliased E (v reads xb/Wb while qk writes E). ids [0,512)=V,
// [512,1056)=QK heavy-first (tail = tiny light strips).
// ---------------------------------------------------------------------------
__global__ __launch_bounds__(256) void vqk_fused(
    const bf16_t* __restrict__ xb, const bf16_t* __restrict__ Wb,
    bf16_t* __restrict__ Vt,
    const bf16_t* __restrict__ QKVb, bf16_t* __restrict__ E,
    float* __restrict__ rowsum)
{
    __shared__ __align__(16) bf16_t As[BM * BK];
    __shared__ __align__(16) bf16_t Bs[BN * BK];
    const int id = blockIdx.x;
    if (id < 512) {
        const int xcd = id & 7;
        const int j   = id >> 3;               // 0..63
        const int mblk = xcd * 8 + (j >> 3);   // 0..63
        const int nblk = j & 7;                // 0..7
        gemm_body<4>(As, Bs, xb, 1024, Wb, 1024, Vt, 2048,
                     0, 1024, 1.0f, mblk * BM, 2048 + nblk * BN, nullptr);
    } else {
        const int qid = id - 512;              // 0..543
        const int b = qid & 3;
        int rem = qid >> 2;                    // 0..135
        int my = 15, nx = 0;
#pragma unroll
        for (int m = 15; m >= 0; --m) {        // heavy strips first
            if (rem < m + 1) { my = m; nx = rem; break; }
            rem -= m + 1;
        }
        const bf16_t* base = QKVb + (size_t)b * (2048L * 2048);
        gemm_body<3>(As, Bs,
                     base + 1024, 2048,        // Q
                     base, 2048,               // K
                     E + (size_t)b * (2048L * 2048), 2048,
                     0, 1024, 0.03125f, my * BM, nx * BN,
                     rowsum + b * 2048);
    }
}

// --------------------- fallback serial pair (small ws) ---------------------
__global__ __launch_bounds__(256) void gemm1_v(
    const bf16_t* __restrict__ xb, const bf16_t* __restrict__ Wb,
    bf16_t* __restrict__ Vt)
{
    __shared__ __align__(16) bf16_t As[BM * BK];
    __shared__ __align__(16) bf16_t Bs[BN * BK];
    const int lin = blockIdx.x;
    const int xcd = lin & 7;
    const int j   = lin >> 3;
    const int mblk = xcd * 8 + (j >> 3);
    const int nblk = j & 7;
    gemm_body<4>(As, Bs, xb, 1024, Wb, 1024, Vt, 2048,
                 0, 1024, 1.0f, mblk * BM, 2048 + nblk * BN, nullptr);
}

__global__ __launch_bounds__(256) void qk_gemm(
    const bf16_t* __restrict__ QKVb, bf16_t* __restrict__ E,
    float* __restrict__ rowsum)
{
    __shared__ __align__(16) bf16_t As[BM * BK];
    __shared__ __align__(16) bf16_t Bs[BN * BK];
    const int b = blockIdx.x & 3;
    int rem = blockIdx.x >> 2;
    int my = 15, nx = 0;
#pragma unroll
    for (int m = 15; m >= 0; --m) {
        if (rem < m + 1) { my = m; nx = rem; break; }
        rem -= m + 1;
    }
    const bf16_t* base = QKVb + (size_t)b * (2048L * 2048);
    gemm_body<3>(As, Bs,
                 base + 1024, 2048,
                 base, 2048,
                 E + (size_t)b * (2048L * 2048), 2048,
                 0, 1024, 0.03125f, my * BM, nx * BN,
                 rowsum + b * 2048);
}

// ---------------------------------------------------------------------------
// GEMM3: out = (E * Vt^T) / rowsum per batch -> f32. tri-K (Keff=m0+128),
// grid 512, heavy strips first, batch fastest.
// ---------------------------------------------------------------------------
__global__ __launch_bounds__(256) void gemm3_pv(
    const bf16_t* __restrict__ E, const bf16_t* __restrict__ Vt,
    const float* __restrict__ rowsum, float* __restrict__ out)
{
    __shared__ __align__(16) bf16_t As[BM * BK];
    __shared__ __align__(16) bf16_t Bs[BN * BK];
    const int id = blockIdx.x;
    const int strip = 15 - (id >> 5);      // heavy first
    const int nx = (id >> 2) & 7;
    const int b = id & 3;
    const int m0 = strip * BM;
    gemm_body<2>(As, Bs,
                 E + (size_t)b * (2048L * 2048), 2048,
                 Vt + (size_t)b * (1024L * 2048), 2048,
                 out + (size_t)b * (2048L * 1024), 1024,
                 0, m0 + BM, 1.0f, m0, nx * BN,
                 (float*)rowsum + b * 2048);
}

// ---------------------------------------------------------------------------
// Merged input casts: blocks [0,8192) cast x, [8192,11264) cast W,
// [11264,11272) zero the rowsum array (4x2048 f32).
__global__ __launch_bounds__(256) void cast_all(
    const float* __restrict__ x,
    const float* __restrict__ Wk, const float* __restrict__ Wq,
    const float* __restrict__ Wv,
    bf16_t* __restrict__ xb, bf16_t* __restrict__ Wb,
    float* __restrict__ rowsum)
{
    const int blk = blockIdx.x;
    if (blk >= 11264) {
        const size_t i = ((size_t)(blk - 11264) * 256 + threadIdx.x) * 4;
        *(float4*)(rowsum + i) = make_float4(0.f, 0.f, 0.f, 0.f);
        return;
    }
    const float* src;
    bf16_t* dst;
    if (blk < 8192) {
        const size_t i = ((size_t)blk * 256 + threadIdx.x) * 4;
        src = x + i;
        dst = xb + i;
    } else {
        const size_t j = ((size_t)(blk - 8192) * 256 + threadIdx.x) * 4;
        dst = Wb + j;
        if (j < (size_t)1048576)      src = Wk + j;
        else if (j < (size_t)2097152) src = Wq + (j - 1048576);
        else                          src = Wv + (j - 2097152);
    }
    const float4 v = *(const float4*)src;
    bf16x4 o;
    o.x = (bf16_t)v.x; o.y = (bf16_t)v.y; o.z = (bf16_t)v.z; o.w = (bf16_t)v.w;
    *(bf16x4*)dst = o;
}

// ---------------------------------------------------------------------------
extern "C" void kernel_launch(void* const* d_in, const int* in_sizes, int n_in,
                              void* d_out, int out_size, void* d_ws, size_t ws_size,
                              hipStream_t stream)
{
    const float* x  = (const float*)d_in[0];
    const float* Wk = (const float*)d_in[1];
    const float* Wq = (const float*)d_in[2];
    const float* Wv = (const float*)d_in[3];
    char* ws = (char*)d_ws;

    // ws layout:
    //   [0,32)    QKVb bf16 8192x2048  ([K|Q] columns; V goes to Vt)
    //   [32,48)   Vt   bf16 4 x 1024x2048 (written transposed)
    //   [48,64)   xb   bf16 8192x1024
    //   [64,70)   Wb   bf16 3072x1024
    // big-ws (>=107 MB): E at [72,105.6) NON-ALIASED (enables v+qk fusion),
    //   rowsum at [106,...). small-ws fallback: E aliases xb+Wb at [48,80),
    //   rowsum at [80,...), v/qk serialized.
    bf16_t* QKVb = (bf16_t*)(ws);
    bf16_t* Vt   = (bf16_t*)(ws + ((size_t)32 << 20));
    bf16_t* xb   = (bf16_t*)(ws + ((size_t)48 << 20));
    bf16_t* Wb   = (bf16_t*)(ws + ((size_t)64 << 20));
    const bool big = ws_size >= ((size_t)107 << 20);
    bf16_t* E      = (bf16_t*)(ws + ((size_t)(big ? 72 : 48) << 20));
    float*  rowsum = (float*)(ws + ((size_t)(big ? 106 : 80) << 20));
    float*  out    = (float*)d_out;

    // 1. cast inputs to bf16 + zero rowsum
    cast_all<<<11272, 256, 0, stream>>>(x, Wk, Wq, Wv, xb, Wb, rowsum);

    // 2. GEMM1 K|Q
    gemm1_kq<<<256, 512, 0, stream>>>(xb, Wb, QKVb);

    // 3. V-projection + causal exp(QK^T) fused (or serial fallback)
    if (big) {
        vqk_fused<<<1056, 256, 0, stream>>>(xb, Wb, Vt, QKVb, E, rowsum);
    } else {
        gemm1_v<<<512, 256, 0, stream>>>(xb, Wb, Vt);
        qk_gemm<<<544, 256, 0, stream>>>(QKVb, E, rowsum);
    }

    // 4. GEMM3: out = (E Vt^T)/rowsum, tri-K, heavy-first
    gemm3_pv<<<512, 256, 0, stream>>>(E, Vt, rowsum, out);
}

// Round 5
// 221.357 us; speedup vs baseline: 1.0355x; 1.0153x over previous
//
#include <hip/hip_runtime.h>
#include <hip/hip_bf16.h>
#include <hip/hip_fp16.h>
#include <stdint.h>

typedef __bf16 bf16_t;
typedef bf16_t bf16x8 __attribute__((ext_vector_type(8)));
typedef bf16_t bf16x4 __attribute__((ext_vector_type(4)));
typedef float f32x4 __attribute__((ext_vector_type(4)));

#define BM 128
#define BN 128
#define BK 64

// async global->LDS, 16B per lane. LDS dst is wave-uniform base + lane*16;
// the GLOBAL source may be arbitrary per-lane (used for the bank swizzle).
__device__ __forceinline__ void gload_lds16(const void* g, void* l) {
    __builtin_amdgcn_global_load_lds(
        (const __attribute__((address_space(1))) void*)(uintptr_t)g,
        (__attribute__((address_space(3))) void*)(uintptr_t)l,
        16, 0, 0);
}

// ---------------------------------------------------------------------------
// 128x128 body, BK=64 as TWO stacked BK=32 sub-tiles As[2][128][32] (r5).
// r4's flat 128B-row layout hit 4.3M bank conflicts (rows are bank-aligned
// at 128B, so rotation can't spread banks). Each half here uses the
// BK=32 layout that measured 0 conflicts: staging slot s of row r holds
// global chunk ((s-(r>>1))&3) (compensated on the per-lane global source),
// read at phys chunk ((hw+(r>>1))&3). One barrier pair per 64 K (the BK=64
// win) with the verified bank pattern (the BK=32 win).
// EPI: 2 = f32 store / rs[row]  (gemm3)
//      3 = exp+causal bf16 store + atomic row-sum into rs  (qk)
//      4 = bf16 transposed into Vt[b][d][s]  (gemm1 V)
// ---------------------------------------------------------------------------
template <int EPI>
__device__ __forceinline__ void gemm_body(
    bf16_t* __restrict__ As, bf16_t* __restrict__ Bs,
    const bf16_t* __restrict__ A, long lda,
    const bf16_t* __restrict__ B, long ldb,
    void* __restrict__ Cv, long ldc,
    int k0beg, int k1end, float scale, int m0, int n0,
    float* __restrict__ rs)
{
    const int tid = threadIdx.x;
    const int wid = tid >> 6, lane = tid & 63;
    const int wr = wid >> 1, wc = wid & 1;
    const int hw = lane >> 4, ln = lane & 15;

    // staging geometry (per half, identical to the verified BK=32 pattern):
    // row0 = tid>>2 in [0,64), slot = tid&3, j = ((slot - (row>>1))&3) is
    // i-invariant; iteration i covers k-half (i>>1), row block (i&1)*64.
    const int row0 = tid >> 2;                       // 0..63
    const int jj = ((tid & 3) - (tid >> 3)) & 3;     // swizzle-compensated chunk
    const bf16_t* srcA0 = A + (size_t)(m0 + row0) * lda + jj * 8;
    const bf16_t* srcB0 = B + (size_t)(n0 + row0) * ldb + jj * 8;

    f32x4 acc[4][4] = {};

    for (int k0 = k0beg; k0 < k1end; k0 += BK) {
#pragma unroll
        for (int i = 0; i < 4; i++) {
            const size_t roff = (size_t)((i & 1) * 64);
            const int koff = k0 + (i >> 1) * 32;
            gload_lds16(srcA0 + roff * lda + koff, &As[i * 2048 + tid * 8]);
            gload_lds16(srcB0 + roff * ldb + koff, &Bs[i * 2048 + tid * 8]);
        }
        __syncthreads();

#pragma unroll
        for (int h = 0; h < 2; h++) {
            bf16x8 af[4], bfr[4];
#pragma unroll
            for (int t = 0; t < 4; t++) {
                const int r  = wr * 64 + t * 16 + ln;
                const int rb = wc * 64 + t * 16 + ln;
                af[t]  = *(const bf16x8*)&As[h * 4096 + r  * 32 + (((hw + (r  >> 1)) & 3) * 8)];
                bfr[t] = *(const bf16x8*)&Bs[h * 4096 + rb * 32 + (((hw + (rb >> 1)) & 3) * 8)];
            }
#pragma unroll
            for (int ti = 0; ti < 4; ti++)
#pragma unroll
                for (int tj = 0; tj < 4; tj++)
                    acc[ti][tj] = __builtin_amdgcn_mfma_f32_16x16x32_bf16(
                        af[ti], bfr[tj], acc[ti][tj], 0, 0, 0);
        }
        __syncthreads();
    }

    // epilogue: C/D layout col=lane&15, row=(lane>>4)*4+reg (m89-verified)
#pragma unroll
    for (int ti = 0; ti < 4; ti++) {
        const int rbase = m0 + wr * 64 + ti * 16 + hw * 4;
        f32x4 inv4;
        if (EPI == 2) {
            const float4 r4 = *(const float4*)&rs[rbase];
            inv4[0] = 1.0f / r4.x; inv4[1] = 1.0f / r4.y;
            inv4[2] = 1.0f / r4.z; inv4[3] = 1.0f / r4.w;
        }
        float part[4] = {0.f, 0.f, 0.f, 0.f};
#pragma unroll
        for (int tj = 0; tj < 4; tj++) {
            const int col = n0 + wc * 64 + tj * 16 + ln;
            if (EPI == 4) {
                // transposed bf16: 4 consecutive rows -> 8B contiguous in Vt
                const int bb = rbase >> 11;
                const int s  = rbase & 2047;
                const int d  = col - 2048;
                bf16x4 o;
#pragma unroll
                for (int rg = 0; rg < 4; rg++) o[rg] = (bf16_t)acc[ti][tj][rg];
                *(bf16x4*)&((bf16_t*)Cv)[(size_t)bb * 2097152 + (size_t)d * 2048 + s] = o;
            } else {
#pragma unroll
                for (int rg = 0; rg < 4; rg++) {
                    const size_t idx = (size_t)(rbase + rg) * ldc + col;
                    if (EPI == 2) {
                        ((float*)Cv)[idx] = acc[ti][tj][rg] * inv4[rg];
                    } else {  // EPI 3: exp + causal mask + row-sum
                        const float e = (col <= rbase + rg)
                                      ? __expf(acc[ti][tj][rg] * scale) : 0.0f;
                        part[rg] += e;
                        ((bf16_t*)Cv)[idx] = (bf16_t)e;
                    }
                }
            }
        }
        if (EPI == 3) {
#pragma unroll
            for (int rg = 0; rg < 4; rg++) {
                float p = part[rg];
                p += __shfl_xor(p, 1, 64);
                p += __shfl_xor(p, 2, 64);
                p += __shfl_xor(p, 4, 64);
                p += __shfl_xor(p, 8, 64);
                if (ln == 0) atomicAdd(&rs[rbase + rg], p);
            }
        }
    }
}

// ---------------------------------------------------------------------------
// 256x256 8-phase body for gemm1 K|Q (r3: ~parity with old body at K=1024;
// kept — not a regression, and a future schedule fix slots in here).
// ---------------------------------------------------------------------------
__device__ __forceinline__ void gemm256_body(
    bf16_t* __restrict__ lds,
    const bf16_t* __restrict__ A, long lda,
    const bf16_t* __restrict__ B, long ldb,
    bf16_t* __restrict__ C, long ldc,
    int nt, int m0, int n0)
{
    const int tid = threadIdx.x;
    const int wid = tid >> 6, lane = tid & 63;
    const int wr = wid >> 2, wcn = wid & 3;
    const int hw = lane >> 4, ln = lane & 15;

    const int srow = (wid << 3) + (lane >> 3);          // 0..63
    const int clog = ((lane & 7) - (lane >> 3)) & 7;    // swizzle-compensated chunk
    const bf16_t* sA = A + (size_t)(m0 + srow) * lda + clog * 8;
    const bf16_t* sB = B + (size_t)(n0 + srow) * ldb + clog * 8;
    char* ldsc = (char*)lds;
    const int wb = wid << 10;

#define STG_A(bf, q, kt) gload_lds16(sA + (size_t)(q) * 64 * lda + (size_t)(kt) * 64, \
                                     ldsc + (bf) * 65536 + (q) * 8192 + wb)
#define STG_B(bf, q, kt) gload_lds16(sB + (size_t)(q) * 64 * ldb + (size_t)(kt) * 64, \
                                     ldsc + (bf) * 65536 + 32768 + (q) * 8192 + wb)

    const int c0 = ((hw + ln) & 7) << 4;
    const int c1 = ((hw + ln + 4) & 7) << 4;
    const int aR = (wr * 128 + ln) * 128;
    const int bR = 32768 + (wcn * 64 + ln) * 128;

#define RDA(bf, fr, ks) (*(const bf16x8*)(ldsc + (bf) * 65536 + aR + (fr) * 2048 + ((ks) ? c1 : c0)))
#define RDB(bf, fc, ks) (*(const bf16x8*)(ldsc + (bf) * 65536 + bR + (fc) * 2048 + ((ks) ? c1 : c0)))

    f32x4 acc[8][4] = {};

    STG_A(0, 0, 0); STG_A(0, 2, 0); STG_B(0, 0, 0); STG_B(0, 1, 0);
    STG_A(0, 1, 0); STG_A(0, 3, 0); STG_B(0, 2, 0); STG_B(0, 3, 0);
    STG_A(1, 0, 1); STG_A(1, 2, 1); STG_B(1, 0, 1); STG_B(1, 1, 1);
    STG_A(1, 1, 1); STG_A(1, 3, 1);
    asm volatile("s_waitcnt vmcnt(6)" ::: "memory");
    __builtin_amdgcn_s_barrier();

    for (int t = 0; t < nt; ++t) {
        const int bc = t & 1, bn = bc ^ 1;
        const int kt1 = (t + 1) & (nt - 1);
        const int kt2 = (t + 2) & (nt - 1);
        bf16x8 af[4][2], bl[2][2], bh[2][2];

        // ---- P1: read a_lo + b_lo; stage t+1's B q2,q3; MFMA Q(0,0)
#pragma unroll
        for (int fr = 0; fr < 4; ++fr) {
            af[fr][0] = RDA(bc, fr, 0);
            af[fr][1] = RDA(bc, fr, 1);
        }
#pragma unroll
        for (int fc = 0; fc < 2; ++fc) {
            bl[fc][0] = RDB(bc, fc, 0);
            bl[fc][1] = RDB(bc, fc, 1);
        }
        STG_B(bn, 2, kt1); STG_B(bn, 3, kt1);
        __builtin_amdgcn_s_barrier();
        asm volatile("s_waitcnt lgkmcnt(0)" ::: "memory");
        __builtin_amdgcn_sched_barrier(0);
        __builtin_amdgcn_s_setprio(1);
#pragma unroll
        for (int fr = 0; fr < 4; ++fr)
#pragma unroll
            for (int fc = 0; fc < 2; ++fc)
#pragma unroll
                for (int ks = 0; ks < 2; ++ks)
                    acc[fr][fc] = __builtin_amdgcn_mfma_f32_16x16x32_bf16(
                        af[fr][ks], bl[fc][ks], acc[fr][fc], 0, 0, 0);
        __builtin_amdgcn_s_setprio(0);
        __builtin_amdgcn_s_barrier();

        // ---- P2: read b_hi; stage t+2 A q0,q2; MFMA Q(0,1)
#pragma unroll
        for (int fc = 0; fc < 2; ++fc) {
            bh[fc][0] = RDB(bc, fc + 2, 0);
            bh[fc][1] = RDB(bc, fc + 2, 1);
        }
        STG_A(bc, 0, kt2); STG_A(bc, 2, kt2);
        __builtin_amdgcn_s_barrier();
        asm volatile("s_waitcnt lgkmcnt(0)" ::: "memory");
        __builtin_amdgcn_sched_barrier(0);
        __builtin_amdgcn_s_setprio(1);
#pragma unroll
        for (int fr = 0; fr < 4; ++fr)
#pragma unroll
            for (int fc = 0; fc < 2; ++fc)
#pragma unroll
                for (int ks = 0; ks < 2; ++ks)
                    acc[fr][fc + 2] = __builtin_amdgcn_mfma_f32_16x16x32_bf16(
                        af[fr][ks], bh[fc][ks], acc[fr][fc + 2], 0, 0, 0);
        __builtin_amdgcn_s_setprio(0);
        __builtin_amdgcn_s_barrier();

        // ---- P3: read a_hi; stage t+2 B q0,q1; MFMA Q(1,1)
#pragma unroll
        for (int fr = 0; fr < 4; ++fr) {
            af[fr][0] = RDA(bc, fr + 4, 0);
            af[fr][1] = RDA(bc, fr + 4, 1);
        }
        STG_B(bc, 0, kt2); STG_B(bc, 1, kt2);
        __builtin_amdgcn_s_barrier();
        asm volatile("s_waitcnt lgkmcnt(0)" ::: "memory");
        __builtin_amdgcn_sched_barrier(0);
        __builtin_amdgcn_s_setprio(1);
#pragma unroll
        for (int fr = 0; fr < 4; ++fr)
#pragma unroll
            for (int fc = 0; fc < 2; ++fc)
#pragma unroll
                for (int ks = 0; ks < 2; ++ks)
                    acc[fr + 4][fc + 2] = __builtin_amdgcn_mfma_f32_16x16x32_bf16(
                        af[fr][ks], bh[fc][ks], acc[fr + 4][fc + 2], 0, 0, 0);
        __builtin_amdgcn_s_setprio(0);
        __builtin_amdgcn_s_barrier();

        // ---- P4: stage t+2 A q1,q3; MFMA Q(1,0); counted vmcnt
        STG_A(bc, 1, kt2); STG_A(bc, 3, kt2);
        __builtin_amdgcn_s_setprio(1);
#pragma unroll
        for (int fr = 0; fr < 4; ++fr)
#pragma unroll
            for (int fc = 0; fc < 2; ++fc)
#pragma unroll
                for (int ks = 0; ks < 2; ++ks)
                    acc[fr + 4][fc] = __builtin_amdgcn_mfma_f32_16x16x32_bf16(
                        af[fr][ks], bl[fc][ks], acc[fr + 4][fc], 0, 0, 0);
        __builtin_amdgcn_s_setprio(0);
        asm volatile("s_waitcnt vmcnt(6)" ::: "memory");
        __builtin_amdgcn_s_barrier();
    }

    asm volatile("s_waitcnt vmcnt(0)" ::: "memory");

#pragma unroll
    for (int fr = 0; fr < 8; ++fr) {
        const int rbase = m0 + wr * 128 + fr * 16 + hw * 4;
#pragma unroll
        for (int fc = 0; fc < 4; ++fc) {
            const int col = n0 + wcn * 64 + fc * 16 + ln;
#pragma unroll
            for (int rg = 0; rg < 4; rg++)
                C[(size_t)(rbase + rg) * ldc + col] = (bf16_t)acc[fr][fc][rg];
        }
    }
#undef STG_A
#undef STG_B
#undef RDA
#undef RDB
}

// ---------------------------------------------------------------------------
// GEMM1a: [K|Q] = x*W^T row-major into QKVb (8192x2048). grid exactly 256.
// ---------------------------------------------------------------------------
__global__ __launch_bounds__(512, 2) void gemm1_kq(
    const bf16_t* __restrict__ xb, const bf16_t* __restrict__ Wb,
    bf16_t* __restrict__ QKVb)
{
    __shared__ __align__(16) bf16_t lds[65536];   // 128 KiB
    const int lin = blockIdx.x;                   // 0..255
    const int xcd = lin & 7;
    const int j   = lin >> 3;                     // 0..31
    const int mblk = xcd * 4 + (j & 3);           // 0..31
    const int nblk = j >> 2;                      // 0..7
    gemm256_body(lds, xb, 1024, Wb, 1024, QKVb, 2048, 16, mblk * 256, nblk * 256);
}

// ---------------------------------------------------------------------------
// FUSED V-projection + QK-exp: independent once kq is done. ids [0,512)=V,
// [512,1056)=QK heavy-first.
// ---------------------------------------------------------------------------
__global__ __launch_bounds__(256) void vqk_fused(
    const bf16_t* __restrict__ xb, const bf16_t* __restrict__ Wb,
    bf16_t* __restrict__ Vt,
    const bf16_t* __restrict__ QKVb, bf16_t* __restrict__ E,
    float* __restrict__ rowsum)
{
    __shared__ __align__(16) bf16_t As[BM * BK];
    __shared__ __align__(16) bf16_t Bs[BN * BK];
    const int id = blockIdx.x;
    if (id < 512) {
        const int xcd = id & 7;
        const int j   = id >> 3;               // 0..63
        const int mblk = xcd * 8 + (j >> 3);   // 0..63
        const int nblk = j & 7;                // 0..7
        gemm_body<4>(As, Bs, xb, 1024, Wb, 1024, Vt, 2048,
                     0, 1024, 1.0f, mblk * BM, 2048 + nblk * BN, nullptr);
    } else {
        const int qid = id - 512;              // 0..543
        const int b = qid & 3;
        int rem = qid >> 2;                    // 0..135
        int my = 15, nx = 0;
#pragma unroll
        for (int m = 15; m >= 0; --m) {        // heavy strips first
            if (rem < m + 1) { my = m; nx = rem; break; }
            rem -= m + 1;
        }
        const bf16_t* base = QKVb + (size_t)b * (2048L * 2048);
        gemm_body<3>(As, Bs,
                     base + 1024, 2048,        // Q
                     base, 2048,               // K
                     E + (size_t)b * (2048L * 2048), 2048,
                     0, 1024, 0.03125f, my * BM, nx * BN,
                     rowsum + b * 2048);
    }
}

// --------------------- fallback serial pair (small ws) ---------------------
__global__ __launch_bounds__(256) void gemm1_v(
    const bf16_t* __restrict__ xb, const bf16_t* __restrict__ Wb,
    bf16_t* __restrict__ Vt)
{
    __shared__ __align__(16) bf16_t As[BM * BK];
    __shared__ __align__(16) bf16_t Bs[BN * BK];
    const int lin = blockIdx.x;
    const int xcd = lin & 7;
    const int j   = lin >> 3;
    const int mblk = xcd * 8 + (j >> 3);
    const int nblk = j & 7;
    gemm_body<4>(As, Bs, xb, 1024, Wb, 1024, Vt, 2048,
                 0, 1024, 1.0f, mblk * BM, 2048 + nblk * BN, nullptr);
}

__global__ __launch_bounds__(256) void qk_gemm(
    const bf16_t* __restrict__ QKVb, bf16_t* __restrict__ E,
    float* __restrict__ rowsum)
{
    __shared__ __align__(16) bf16_t As[BM * BK];
    __shared__ __align__(16) bf16_t Bs[BN * BK];
    const int b = blockIdx.x & 3;
    int rem = blockIdx.x >> 2;
    int my = 15, nx = 0;
#pragma unroll
    for (int m = 15; m >= 0; --m) {
        if (rem < m + 1) { my = m; nx = rem; break; }
        rem -= m + 1;
    }
    const bf16_t* base = QKVb + (size_t)b * (2048L * 2048);
    gemm_body<3>(As, Bs,
                 base + 1024, 2048,
                 base, 2048,
                 E + (size_t)b * (2048L * 2048), 2048,
                 0, 1024, 0.03125f, my * BM, nx * BN,
                 rowsum + b * 2048);
}

// ---------------------------------------------------------------------------
// GEMM3: out = (E * Vt^T) / rowsum per batch -> f32. tri-K (Keff=m0+128),
// grid 512, heavy strips first, batch fastest.
// ---------------------------------------------------------------------------
__global__ __launch_bounds__(256) void gemm3_pv(
    const bf16_t* __restrict__ E, const bf16_t* __restrict__ Vt,
    const float* __restrict__ rowsum, float* __restrict__ out)
{
    __shared__ __align__(16) bf16_t As[BM * BK];
    __shared__ __align__(16) bf16_t Bs[BN * BK];
    const int id = blockIdx.x;
    const int strip = 15 - (id >> 5);      // heavy first
    const int nx = (id >> 2) & 7;
    const int b = id & 3;
    const int m0 = strip * BM;
    gemm_body<2>(As, Bs,
                 E + (size_t)b * (2048L * 2048), 2048,
                 Vt + (size_t)b * (1024L * 2048), 2048,
                 out + (size_t)b * (2048L * 1024), 1024,
                 0, m0 + BM, 1.0f, m0, nx * BN,
                 (float*)rowsum + b * 2048);
}

// ---------------------------------------------------------------------------
// Merged input casts: blocks [0,8192) cast x, [8192,11264) cast W,
// [11264,11272) zero the rowsum array (4x2048 f32).
__global__ __launch_bounds__(256) void cast_all(
    const float* __restrict__ x,
    const float* __restrict__ Wk, const float* __restrict__ Wq,
    const float* __restrict__ Wv,
    bf16_t* __restrict__ xb, bf16_t* __restrict__ Wb,
    float* __restrict__ rowsum)
{
    const int blk = blockIdx.x;
    if (blk >= 11264) {
        const size_t i = ((size_t)(blk - 11264) * 256 + threadIdx.x) * 4;
        *(float4*)(rowsum + i) = make_float4(0.f, 0.f, 0.f, 0.f);
        return;
    }
    const float* src;
    bf16_t* dst;
    if (blk < 8192) {
        const size_t i = ((size_t)blk * 256 + threadIdx.x) * 4;
        src = x + i;
        dst = xb + i;
    } else {
        const size_t j = ((size_t)(blk - 8192) * 256 + threadIdx.x) * 4;
        dst = Wb + j;
        if (j < (size_t)1048576)      src = Wk + j;
        else if (j < (size_t)2097152) src = Wq + (j - 1048576);
        else                          src = Wv + (j - 2097152);
    }
    const float4 v = *(const float4*)src;
    bf16x4 o;
    o.x = (bf16_t)v.x; o.y = (bf16_t)v.y; o.z = (bf16_t)v.z; o.w = (bf16_t)v.w;
    *(bf16x4*)dst = o;
}

// ---------------------------------------------------------------------------
extern "C" void kernel_launch(void* const* d_in, const int* in_sizes, int n_in,
                              void* d_out, int out_size, void* d_ws, size_t ws_size,
                              hipStream_t stream)
{
    const float* x  = (const float*)d_in[0];
    const float* Wk = (const float*)d_in[1];
    const float* Wq = (const float*)d_in[2];
    const float* Wv = (const float*)d_in[3];
    char* ws = (char*)d_ws;

    // ws layout:
    //   [0,32)    QKVb bf16 8192x2048  ([K|Q] columns; V goes to Vt)
    //   [32,48)   Vt   bf16 4 x 1024x2048 (written transposed)
    //   [48,64)   xb   bf16 8192x1024
    //   [64,70)   Wb   bf16 3072x1024
    // big-ws (>=107 MB): E at [72,105.6) NON-ALIASED (enables v+qk fusion),
    //   rowsum at [106,...). small-ws fallback: E aliases xb+Wb at [48,80),
    //   rowsum at [80,...), v/qk serialized.
    bf16_t* QKVb = (bf16_t*)(ws);
    bf16_t* Vt   = (bf16_t*)(ws + ((size_t)32 << 20));
    bf16_t* xb   = (bf16_t*)(ws + ((size_t)48 << 20));
    bf16_t* Wb   = (bf16_t*)(ws + ((size_t)64 << 20));
    const bool big = ws_size >= ((size_t)107 << 20);
    bf16_t* E      = (bf16_t*)(ws + ((size_t)(big ? 72 : 48) << 20));
    float*  rowsum = (float*)(ws + ((size_t)(big ? 106 : 80) << 20));
    float*  out    = (float*)d_out;

    // 1. cast inputs to bf16 + zero rowsum
    cast_all<<<11272, 256, 0, stream>>>(x, Wk, Wq, Wv, xb, Wb, rowsum);

    // 2. GEMM1 K|Q
    gemm1_kq<<<256, 512, 0, stream>>>(xb, Wb, QKVb);

    // 3. V-projection + causal exp(QK^T) fused (or serial fallback)
    if (big) {
        vqk_fused<<<1056, 256, 0, stream>>>(xb, Wb, Vt, QKVb, E, rowsum);
    } else {
        gemm1_v<<<512, 256, 0, stream>>>(xb, Wb, Vt);
        qk_gemm<<<544, 256, 0, stream>>>(QKVb, E, rowsum);
    }

    // 4. GEMM3: out = (E Vt^T)/rowsum, tri-K, heavy-first
    gemm3_pv<<<512, 256, 0, stream>>>(E, Vt, rowsum, out);
}